// Round 11
// baseline (89.884 us; speedup 1.0000x reference)
//
#include <hip/hip_runtime.h>
#include <hip/hip_bf16.h>
#include <cstdint>

#define NBLK 1024      // graphs
#define NPG  128       // nodes per graph
#define EPG  512       // edges per graph
#define DD   64        // feature dim
#define NSTEP 5        // MAX_STEPS + 1
#define ETOT (NBLK*EPG)
#define NEGF (-1e30f)
#define WAVES 4        // waves per team (graph)
#define TEAMS 4        // graphs per block
#define MAXDEG 32      // P(Poisson(4) > 32) ~ 1e-19 per node; safe cap

// output element offsets (fp32 elements)
#define OA  0
#define OLS 5120
#define OPF 6144
#define OPB 11264
#define OU  16384
#define OSN 540672
#define OST 541696

struct KeysArg {
  uint32_t ke0[NSTEP], ke1[NSTEP];
  uint32_t ks0[NSTEP], ks1[NSTEP];
};

__host__ __device__ inline uint32_t rotl32(uint32_t x, int r){ return (x<<r)|(x>>(32-r)); }

// JAX threefry2x32 (20 rounds), bit-exact
__host__ __device__ inline void tf2x32(uint32_t k0, uint32_t k1, uint32_t& x0, uint32_t& x1){
  uint32_t k2 = k0 ^ k1 ^ 0x1BD11BDAu;
  x0 += k0; x1 += k1;
  x0+=x1; x1=rotl32(x1,13); x1^=x0;
  x0+=x1; x1=rotl32(x1,15); x1^=x0;
  x0+=x1; x1=rotl32(x1,26); x1^=x0;
  x0+=x1; x1=rotl32(x1, 6); x1^=x0;
  x0+=k1; x1+=k2+1u;
  x0+=x1; x1=rotl32(x1,17); x1^=x0;
  x0+=x1; x1=rotl32(x1,29); x1^=x0;
  x0+=x1; x1=rotl32(x1,16); x1^=x0;
  x0+=x1; x1=rotl32(x1,24); x1^=x0;
  x0+=k2; x1+=k0+2u;
  x0+=x1; x1=rotl32(x1,13); x1^=x0;
  x0+=x1; x1=rotl32(x1,15); x1^=x0;
  x0+=x1; x1=rotl32(x1,26); x1^=x0;
  x0+=x1; x1=rotl32(x1, 6); x1^=x0;
  x0+=k0; x1+=k1+3u;
  x0+=x1; x1=rotl32(x1,17); x1^=x0;
  x0+=x1; x1=rotl32(x1,29); x1^=x0;
  x0+=x1; x1=rotl32(x1,16); x1^=x0;
  x0+=x1; x1=rotl32(x1,24); x1^=x0;
  x0+=k1; x1+=k2+4u;
  x0+=x1; x1=rotl32(x1,13); x1^=x0;
  x0+=x1; x1=rotl32(x1,15); x1^=x0;
  x0+=x1; x1=rotl32(x1,26); x1^=x0;
  x0+=x1; x1=rotl32(x1, 6); x1^=x0;
  x0+=k2; x1+=k0+5u;
}

__device__ inline float gumbel_from_bits(uint32_t bits){
  float f = __uint_as_float((bits>>9) | 0x3f800000u) - 1.0f;
  const float tiny = 1.17549435e-38f;
  float u = fmaxf(tiny, f * (1.0f - tiny) + tiny);
  return -logf(-logf(u));
}

__device__ inline float gumbel_part(uint32_t k0, uint32_t k1, uint32_t idx){
  uint32_t x0 = 0u, x1 = idx;
  tf2x32(k0, k1, x0, x1);
  return gumbel_from_bits(x0 ^ x1);
}

__device__ inline float wsum(float x){
  #pragma unroll
  for (int off = 32; off; off >>= 1) x += __shfl_xor(x, off, 64);
  return x;
}

__device__ __forceinline__ void wsum4(float& x0, float& x1, float& x2, float& x3){
  #pragma unroll
  for (int off = 32; off; off >>= 1){
    x0 += __shfl_xor(x0, off, 64);
    x1 += __shfl_xor(x1, off, 64);
    x2 += __shfl_xor(x2, off, 64);
    x3 += __shfl_xor(x3, off, 64);
  }
}

__device__ __forceinline__ float rdlane(float v, int i){
  return __int_as_float(__builtin_amdgcn_readlane(__float_as_int(v), i));
}
__device__ __forceinline__ int rdlane_i(int v, int i){
  return __builtin_amdgcn_readlane(v, i);
}

// column matvec; 4 accs, unroll 4. Acc order identical to rounds 4-10.
// W may point to LDS (compiler infers addrspace after inlining) or global.
__device__ __forceinline__ float matvec_col(const float* __restrict__ W, float v, int lane){
  float a0=0.f, a1=0.f, a2=0.f, a3=0.f;
  #pragma unroll 4
  for (int i = 0; i < DD; i += 4){
    a0 = fmaf(rdlane(v, i  ), W[(i  )*DD+lane], a0);
    a1 = fmaf(rdlane(v, i+1), W[(i+1)*DD+lane], a1);
    a2 = fmaf(rdlane(v, i+2), W[(i+2)*DD+lane], a2);
    a3 = fmaf(rdlane(v, i+3), W[(i+3)*DD+lane], a3);
  }
  return (a0+a1)+(a2+a3);
}

// 4-candidate batched matvec; unroll 8. Per-candidate order == matvec_col.
__device__ __forceinline__ void matvec4(const float* __restrict__ W,
                                        float v0, float v1, float v2, float v3,
                                        int lane, float o[4]){
  float acc[4][4] = {{0,0,0,0},{0,0,0,0},{0,0,0,0},{0,0,0,0}};
  #pragma unroll 8
  for (int i = 0; i < DD; i += 4){
    #pragma unroll
    for (int t = 0; t < 4; t++){
      float w  = W[(i+t)*DD+lane];
      acc[0][t] = fmaf(rdlane(v0, i+t), w, acc[0][t]);
      acc[1][t] = fmaf(rdlane(v1, i+t), w, acc[1][t]);
      acc[2][t] = fmaf(rdlane(v2, i+t), w, acc[2][t]);
      acc[3][t] = fmaf(rdlane(v3, i+t), w, acc[3][t]);
    }
  }
  #pragma unroll
  for (int c = 0; c < 4; c++)
    o[c] = (acc[c][0]+acc[c][1])+(acc[c][2]+acc[c][3]);
}

// 4 graphs per 1024-thread block (1 block/CU via 128KB LDS); hot weights in LDS.
// Per team: R10 schedule. Barriers are block-wide and UNCONDITIONAL per step.
__global__ void __launch_bounds__(1024)
gfn_fused(const float* __restrict__ node_tokens,
          const float* __restrict__ edge_emb,
          const float* __restrict__ Wf1, const float* __restrict__ Wnf, const float* __restrict__ Wf2,
          const float* __restrict__ bf,  const float* __restrict__ wf,
          const float* __restrict__ Wb1, const float* __restrict__ Wnb, const float* __restrict__ Wb2,
          const float* __restrict__ bb,  const float* __restrict__ wb,
          const float* __restrict__ w_stop, const float* __restrict__ b_stop,
          const float* __restrict__ Ws,  const float* __restrict__ Wu, const float* __restrict__ bu,
          const int* __restrict__ e_src, const int* __restrict__ e_dst,
          float* __restrict__ out, KeysArg keys)
{
  const int tid  = threadIdx.x;          // 0..1023
  const int team = tid >> 8;             // 0..3
  const int ttid = tid & 255;            // thread within team
  const int lane = tid & 63;
  const int wave = (tid >> 6) & 3;       // wave within team
  const int g    = blockIdx.x * TEAMS + team;
  const int ebase = g * EPG;

  __shared__ float Wlds[6][DD*DD];       // 0=Wf1 1=Wb1 2=Wnf 3=Wnb 4=Wf2 5=Wb2
  __shared__ uint8_t  srcL[TEAMS][EPG], dstL[TEAMS][EPG];
  __shared__ uint16_t listO[TEAMS][EPG], listI[TEAMS][EPG];
  __shared__ int cntO[TEAMS][NPG], cntI[TEAMS][NPG], begO[TEAMS][NPG], begI[TEAMS][NPG];
  __shared__ uint8_t usedL[TEAMS][EPG];
  __shared__ float st_sh[TEAMS][DD];
  __shared__ float u_sh[TEAMS][DD], nt_sh[TEAMS][DD], acs_sh[TEAMS][DD];
  __shared__ float ntb_sh[TEAMS][DD], ntN_sh[TEAMS][DD], uN_sh[TEAMS][DD], ubB_sh[TEAMS][DD];
  __shared__ float xcF[TEAMS][MAXDEG], gmF[TEAMS][MAXDEG], xcB[TEAMS][MAXDEG];
  __shared__ float sl_sh[TEAMS], xbb_sh[TEAMS];

  // ---- stage hot weights to LDS (1 float4 per thread per matrix) ----
  {
    const float* srcs[6] = {Wf1, Wb1, Wnf, Wnb, Wf2, Wb2};
    #pragma unroll
    for (int m = 0; m < 6; m++)
      ((float4*)&Wlds[m][0])[tid] = ((const float4*)srcs[m])[tid];
  }

  // ---- load edges, init (team-local) ----
  for (int j = ttid; j < EPG; j += 256){
    srcL[team][j] = (uint8_t)(e_src[ebase+j] - g*NPG);
    dstL[team][j] = (uint8_t)(e_dst[ebase+j] - g*NPG);
    usedL[team][j] = 0;
  }
  for (int n = ttid; n < NPG; n += 256){ cntO[team][n]=0; cntI[team][n]=0; }
  if (ttid < DD) st_sh[team][ttid] = 0.f;
  __syncthreads();

  for (int j = ttid; j < EPG; j += 256){
    atomicAdd(&cntO[team][srcL[team][j]], 1);
    atomicAdd(&cntI[team][dstL[team][j]], 1);
  }
  __syncthreads();

  if (wave == 0){                                   // each team's wave 0
    int n0 = lane*2, n1 = n0+1;
    int c0O=cntO[team][n0], c1O=cntO[team][n1], sO=c0O+c1O;
    int c0I=cntI[team][n0], c1I=cntI[team][n1], sI=c0I+c1I;
    int xO=sO, xI=sI;
    #pragma unroll
    for (int off=1; off<64; off<<=1){
      int tO=__shfl_up(xO,off,64), tI=__shfl_up(xI,off,64);
      if (lane>=off){ xO+=tO; xI+=tI; }
    }
    begO[team][n0]=xO-sO; begO[team][n1]=xO-c1O;
    begI[team][n0]=xI-sI; begI[team][n1]=xI-c1I;
  }
  __syncthreads();
  for (int n = ttid; n < NPG; n += 256){ cntO[team][n]=0; cntI[team][n]=0; }
  __syncthreads();

  for (int ph = 0; ph < WAVES; ph++){
    if (wave == ph){
      #pragma unroll
      for (int h = 0; h < 2; h++){
        int j = ph*128 + h*64 + lane;
        int sL = srcL[team][j]; int p = atomicAdd(&cntO[team][sL],1); listO[team][begO[team][sL]+p] = (uint16_t)j;
        int dL = dstL[team][j]; int q = atomicAdd(&cntI[team][dL],1); listI[team][begI[team][dL]+q] = (uint16_t)j;
      }
    }
    __syncthreads();
  }

  const float bf_l = bf[lane], wf_l = wf[lane];
  const float bb_l = bb[lane], wb_l = wb[lane];
  const float bu_l = bu[lane], wst_l = w_stop[lane];
  const float bstop = b_stop[0];

  bool done = false;
  int stepsC = 0, stopn = -1, activeL = 0;
  float lpf_sum = 0.f;
  int bOF = begO[team][0], dOF = min(cntO[team][0], MAXDEG);

  // ---- prologue: Phase A (dense) + A2 (fwd candidates for step 0) ----
  {
    float st_v = st_sh[team][lane];
    if (wave == 0)      u_sh[team][lane]   = matvec_col(Wlds[4], st_v, lane);      // Wf2
    else if (wave == 1){ float ntv = node_tokens[(size_t)(g*NPG+0)*DD+lane];
                         nt_sh[team][lane] = matvec_col(Wlds[2], ntv, lane); }     // Wnf
    else if (wave == 2) acs_sh[team][lane] = matvec_col(Ws, st_v, lane);           // speculative
    else {
      float sl = wsum(st_v * wst_l) + bstop;
      if (lane == 0) sl_sh[team] = sl;
      if (lane < dOF)
        gmF[team][lane] = gumbel_part(keys.ke0[0], keys.ke1[0], (uint32_t)(ebase + listO[team][bOF+lane]));
    }
    __syncthreads();
    if (wave >= 2){
      for (int c = wave-2; c < (dOF+3)>>2; c += 2){
        int el[4]; float v[4];
        #pragma unroll
        for (int t = 0; t < 4; t++){
          int k = c*4 + t;
          el[t] = listO[team][bOF + min(k, dOF-1)];
          v[t]  = edge_emb[(size_t)(ebase+el[t])*DD + lane];
        }
        float o[4], x[4];
        matvec4(Wlds[0], v[0], v[1], v[2], v[3], lane, o);                         // Wf1
        #pragma unroll
        for (int t = 0; t < 4; t++) x[t] = fmaxf(o[t] + nt_sh[team][lane] + bf_l + u_sh[team][lane], 0.f) * wf_l;
        wsum4(x[0], x[1], x[2], x[3]);
        #pragma unroll
        for (int t = 0; t < 4; t++){
          int k = c*4 + t;
          if (k < dOF && lane == 0) xcF[team][k] = usedL[team][el[t]] ? NEGF : x[t];
        }
      }
    }
    __syncthreads();
  }

  for (int s = 0; s < NSTEP; s++){
    float act_out = -1.f, lpf_out = 0.f, lpb_out = 0.f;
    bool choose_stop = false, take_edge = false;
    int elbest = -1, newA = 0, bI = 0, dIc = 0, bON = 0, dON = 0;
    const bool more = (s < NSTEP-1);

    if (!done){
      // ---- selection (register-resident candidate data; no barriers) ----
      float xr = (lane < MAXDEG) ? xcF[team][lane] : NEGF;
      float gr = (lane < MAXDEG) ? gmF[team][lane] : 0.f;
      int   er = (lane < dOF)    ? (int)listO[team][bOF + lane] : -1;
      float sl = sl_sh[team];

      float m1 = NEGF; int nvalid = 0;
      for (int k=0;k<dOF;k++){ float xk=rdlane(xr,k); if (xk!=NEGF){ m1=fmaxf(m1,xk); nvalid++; } }
      float ssum = 0.f;
      for (int k=0;k<dOF;k++){ float xk=rdlane(xr,k); if (xk!=NEGF) ssum += expf(xk - m1); }
      const bool has_edge = nvalid > 0;
      float lse_e = m1 + logf(fmaxf(ssum, 1e-30f));
      const bool allow_stop = (stepsC < 4);
      float stop_t = allow_stop ? sl : NEGF;
      float amx = fmaxf(lse_e, stop_t);
      float Z = amx + log1pf(expf(-fabsf(lse_e - stop_t)));

      float mbest = NEGF; float xbest = 0.f;
      for (int k=0;k<dOF;k++){
        float xk = rdlane(xr,k);
        if (xk == NEGF) continue;
        float se = (xk - Z) + rdlane(gr,k);
        if (se > mbest){ mbest = se; elbest = rdlane_i(er,k); xbest = xk; }
      }
      float gs = gumbel_part(keys.ks0[s], keys.ks1[s], (uint32_t)g);
      float ss = allow_stop ? (sl - Z) + gs : NEGF;
      float mcmp = has_edge ? mbest : NEGF;
      choose_stop = (ss > mcmp) || (!has_edge);
      float logp_stop = allow_stop ? (sl - Z) : 0.f;
      take_edge = !choose_stop;

      act_out = choose_stop ? -1.f : (float)(ebase + elbest);
      lpf_out = choose_stop ? logp_stop : (xbest - Z);
      if (choose_stop && stopn < 0) stopn = activeL;
    }

    // ---- Phase B: state' + node-token matvecs ----
    if (take_edge){
      newA = dstL[team][elbest];
      if (wave == 0){
        float rv = edge_emb[(size_t)(ebase+elbest)*DD + lane];
        float acr = matvec_col(Wu, rv, lane);
        st_sh[team][lane] = tanhf(acs_sh[team][lane] + acr + bu_l);
        if (lane == 0) usedL[team][elbest] = 1;
      } else if (wave == 1){
        float nbv = node_tokens[(size_t)(g*NPG + newA)*DD + lane];
        ntb_sh[team][lane] = matvec_col(Wlds[3], nbv, lane);                        // Wnb
      } else if (wave == 2){
        if (more){
          float nbv = node_tokens[(size_t)(g*NPG + newA)*DD + lane];
          ntN_sh[team][lane] = matvec_col(Wlds[2], nbv, lane);                      // Wnf
        }
      }
      activeL = newA; stepsC++;
    }
    __syncthreads();

    // ---- Phase C: st'-dependent matvecs + next gumbels ----
    if (take_edge){
      float stp = st_sh[team][lane];
      bI  = begI[team][activeL]; dIc = min(cntI[team][activeL], MAXDEG);
      bON = begO[team][activeL];
      dON = more ? min(cntO[team][activeL], MAXDEG) : 0;
      if (wave == 0){
        if (more) uN_sh[team][lane] = matvec_col(Wlds[4], stp, lane);               // Wf2
      } else if (wave == 1){
        ubB_sh[team][lane] = matvec_col(Wlds[5], stp, lane);                        // Wb2
      } else if (wave == 2){
        if (more) acs_sh[team][lane] = matvec_col(Ws, stp, lane);
      } else {
        if (more){
          float s2 = wsum(stp * wst_l) + bstop;
          if (lane == 0) sl_sh[team] = s2;
          if (lane < dON)
            gmF[team][lane] = gumbel_part(keys.ke0[s+1], keys.ke1[s+1],
                                          (uint32_t)(ebase + listO[team][bON+lane]));
        }
      }
    }
    __syncthreads();

    // ---- Phase D: bwd candidates (w2,w0) || fwd-next candidates (w3,w1) ----
    if (take_edge){
      if (wave == 2 || wave == 0){
        for (int c = (wave==2 ? 0 : 1); c < (dIc+3)>>2; c += 2){
          int el[4]; float v[4];
          #pragma unroll
          for (int t = 0; t < 4; t++){
            int k = c*4 + t;
            el[t] = listI[team][bI + min(k, dIc-1)];
            v[t]  = edge_emb[(size_t)(ebase+el[t])*DD + lane];
          }
          float o[4], xb[4];
          matvec4(Wlds[1], v[0], v[1], v[2], v[3], lane, o);                        // Wb1
          #pragma unroll
          for (int t = 0; t < 4; t++) xb[t] = fmaxf(o[t] + ntb_sh[team][lane] + bb_l + ubB_sh[team][lane], 0.f) * wb_l;
          wsum4(xb[0], xb[1], xb[2], xb[3]);
          #pragma unroll
          for (int t = 0; t < 4; t++){
            int k = c*4 + t;
            if (k < dIc && lane == 0){
              xcB[team][k] = xb[t];
              if (el[t] == elbest) xbb_sh[team] = xb[t];
            }
          }
        }
      } else {
        for (int c = (wave==3 ? 0 : 1); c < (dON+3)>>2; c += 2){
          int el[4]; float v[4];
          #pragma unroll
          for (int t = 0; t < 4; t++){
            int k = c*4 + t;
            el[t] = listO[team][bON + min(k, dON-1)];
            v[t]  = edge_emb[(size_t)(ebase+el[t])*DD + lane];
          }
          float o[4], x[4];
          matvec4(Wlds[0], v[0], v[1], v[2], v[3], lane, o);                        // Wf1
          #pragma unroll
          for (int t = 0; t < 4; t++) x[t] = fmaxf(o[t] + ntN_sh[team][lane] + bf_l + uN_sh[team][lane], 0.f) * wf_l;
          wsum4(x[0], x[1], x[2], x[3]);
          #pragma unroll
          for (int t = 0; t < 4; t++){
            int k = c*4 + t;
            if (k < dON && lane == 0) xcF[team][k] = usedL[team][el[t]] ? NEGF : x[t];
          }
        }
      }
    }
    __syncthreads();

    // ---- bwd combine ----
    if (take_edge){
      float xbr = (lane < MAXDEG) ? xcB[team][lane] : 0.f;
      float m2 = NEGF;
      for (int k=0;k<dIc;k++) m2 = fmaxf(m2, rdlane(xbr,k));
      float s2 = 0.f;
      for (int k=0;k<dIc;k++) s2 += expf(rdlane(xbr,k) - m2);
      float lse_b = m2 + logf(fmaxf(s2, 1e-30f));
      lpb_out = xbb_sh[team] - lse_b;
      bOF = bON; dOF = dON;
    }
    done = done || choose_stop;

    if (ttid == 0){
      out[OA  + g*NSTEP + s] = act_out;
      out[OPF + g*NSTEP + s] = lpf_out;
      out[OPB + g*NSTEP + s] = lpb_out;
    }
    lpf_sum += lpf_out;
  }

  // ---- finalize ----
  if (ttid == 0){
    out[OLS + g] = lpf_sum;
    int sn = (stopn < 0) ? activeL : stopn;
    out[OSN + g] = (float)sn;
    out[OST + g] = (float)stepsC;
  }
  for (int j = ttid; j < EPG; j += 256)
    out[OU + ebase + j] = usedL[team][j] ? 1.0f : 0.0f;
}

extern "C" void kernel_launch(void* const* d_in, const int* in_sizes, int n_in,
                              void* d_out, int out_size, void* d_ws, size_t ws_size,
                              hipStream_t stream)
{
  (void)in_sizes; (void)n_in; (void)out_size; (void)d_ws; (void)ws_size;

  // JAX key schedule, threefry_partitionable (default since jax 0.4.36)
  KeysArg K;
  for (uint32_t s = 0; s < NSTEP; s++){
    uint32_t a = 0u, b = s;
    tf2x32(0u, 42u, a, b);
    uint32_t e0 = 0u, e1 = 0u;
    tf2x32(a, b, e0, e1);
    uint32_t s0 = 0u, s1 = 1u;
    tf2x32(a, b, s0, s1);
    K.ke0[s] = e0; K.ke1[s] = e1;
    K.ks0[s] = s0; K.ks1[s] = s1;
  }

  const int* eidx = (const int*)d_in[17];
  gfn_fused<<<dim3(NBLK/TEAMS), dim3(1024), 0, stream>>>(
      (const float*)d_in[0],  (const float*)d_in[1],
      (const float*)d_in[2],  (const float*)d_in[3],  (const float*)d_in[4],
      (const float*)d_in[5],  (const float*)d_in[6],
      (const float*)d_in[7],  (const float*)d_in[8],  (const float*)d_in[9],
      (const float*)d_in[10], (const float*)d_in[11],
      (const float*)d_in[12], (const float*)d_in[13],
      (const float*)d_in[14], (const float*)d_in[15], (const float*)d_in[16],
      eidx, eidx + ETOT,
      (float*)d_out, K);
}

// Round 12
// 78.347 us; speedup vs baseline: 1.1472x; 1.1472x over previous
//
#include <hip/hip_runtime.h>
#include <hip/hip_bf16.h>
#include <cstdint>

#define NBLK 1024      // graphs
#define NPG  128       // nodes per graph
#define EPG  512       // edges per graph
#define DD   64        // feature dim
#define NSTEP 5        // MAX_STEPS + 1
#define ETOT (NBLK*EPG)
#define NEGF (-1e30f)
#define WAVES 4
#define MAXDEG 32      // P(Poisson(4) > 32) ~ 1e-19 per node; safe cap

// output element offsets (fp32 elements)
#define OA  0
#define OLS 5120
#define OPF 6144
#define OPB 11264
#define OU  16384
#define OSN 540672
#define OST 541696

struct KeysArg {
  uint32_t ke0[NSTEP], ke1[NSTEP];
  uint32_t ks0[NSTEP], ks1[NSTEP];
};

__host__ __device__ inline uint32_t rotl32(uint32_t x, int r){ return (x<<r)|(x>>(32-r)); }

// JAX threefry2x32 (20 rounds), bit-exact
__host__ __device__ inline void tf2x32(uint32_t k0, uint32_t k1, uint32_t& x0, uint32_t& x1){
  uint32_t k2 = k0 ^ k1 ^ 0x1BD11BDAu;
  x0 += k0; x1 += k1;
  x0+=x1; x1=rotl32(x1,13); x1^=x0;
  x0+=x1; x1=rotl32(x1,15); x1^=x0;
  x0+=x1; x1=rotl32(x1,26); x1^=x0;
  x0+=x1; x1=rotl32(x1, 6); x1^=x0;
  x0+=k1; x1+=k2+1u;
  x0+=x1; x1=rotl32(x1,17); x1^=x0;
  x0+=x1; x1=rotl32(x1,29); x1^=x0;
  x0+=x1; x1=rotl32(x1,16); x1^=x0;
  x0+=x1; x1=rotl32(x1,24); x1^=x0;
  x0+=k2; x1+=k0+2u;
  x0+=x1; x1=rotl32(x1,13); x1^=x0;
  x0+=x1; x1=rotl32(x1,15); x1^=x0;
  x0+=x1; x1=rotl32(x1,26); x1^=x0;
  x0+=x1; x1=rotl32(x1, 6); x1^=x0;
  x0+=k0; x1+=k1+3u;
  x0+=x1; x1=rotl32(x1,17); x1^=x0;
  x0+=x1; x1=rotl32(x1,29); x1^=x0;
  x0+=x1; x1=rotl32(x1,16); x1^=x0;
  x0+=x1; x1=rotl32(x1,24); x1^=x0;
  x0+=k1; x1+=k2+4u;
  x0+=x1; x1=rotl32(x1,13); x1^=x0;
  x0+=x1; x1=rotl32(x1,15); x1^=x0;
  x0+=x1; x1=rotl32(x1,26); x1^=x0;
  x0+=x1; x1=rotl32(x1, 6); x1^=x0;
  x0+=k2; x1+=k0+5u;
}

__device__ inline float gumbel_from_bits(uint32_t bits){
  float f = __uint_as_float((bits>>9) | 0x3f800000u) - 1.0f;
  const float tiny = 1.17549435e-38f;
  float u = fmaxf(tiny, f * (1.0f - tiny) + tiny);
  return -logf(-logf(u));
}

__device__ inline float gumbel_part(uint32_t k0, uint32_t k1, uint32_t idx){
  uint32_t x0 = 0u, x1 = idx;
  tf2x32(k0, k1, x0, x1);
  return gumbel_from_bits(x0 ^ x1);
}

__device__ inline float wsum(float x){
  #pragma unroll
  for (int off = 32; off; off >>= 1) x += __shfl_xor(x, off, 64);
  return x;
}

__device__ __forceinline__ void wsum4(float& x0, float& x1, float& x2, float& x3){
  #pragma unroll
  for (int off = 32; off; off >>= 1){
    x0 += __shfl_xor(x0, off, 64);
    x1 += __shfl_xor(x1, off, 64);
    x2 += __shfl_xor(x2, off, 64);
    x3 += __shfl_xor(x3, off, 64);
  }
}

__device__ __forceinline__ float rdlane(float v, int i){
  return __int_as_float(__builtin_amdgcn_readlane(__float_as_int(v), i));
}
__device__ __forceinline__ int rdlane_i(int v, int i){
  return __builtin_amdgcn_readlane(v, i);
}

// column matvec; 4 accs, unroll 8 (32 loads in flight -> 2 latency round-trips).
// Acc order identical to rounds 4-11.
__device__ __forceinline__ float matvec_col(const float* __restrict__ W, float v, int lane){
  float a0=0.f, a1=0.f, a2=0.f, a3=0.f;
  #pragma unroll 8
  for (int i = 0; i < DD; i += 4){
    a0 = fmaf(rdlane(v, i  ), W[(i  )*DD+lane], a0);
    a1 = fmaf(rdlane(v, i+1), W[(i+1)*DD+lane], a1);
    a2 = fmaf(rdlane(v, i+2), W[(i+2)*DD+lane], a2);
    a3 = fmaf(rdlane(v, i+3), W[(i+3)*DD+lane], a3);
  }
  return (a0+a1)+(a2+a3);
}

// 4-candidate batched matvec; unroll 8. Per-candidate order == matvec_col.
__device__ __forceinline__ void matvec4(const float* __restrict__ W,
                                        float v0, float v1, float v2, float v3,
                                        int lane, float o[4]){
  float acc[4][4] = {{0,0,0,0},{0,0,0,0},{0,0,0,0},{0,0,0,0}};
  #pragma unroll 8
  for (int i = 0; i < DD; i += 4){
    #pragma unroll
    for (int t = 0; t < 4; t++){
      float w  = W[(i+t)*DD+lane];
      acc[0][t] = fmaf(rdlane(v0, i+t), w, acc[0][t]);
      acc[1][t] = fmaf(rdlane(v1, i+t), w, acc[1][t]);
      acc[2][t] = fmaf(rdlane(v2, i+t), w, acc[2][t]);
      acc[3][t] = fmaf(rdlane(v3, i+t), w, acc[3][t]);
    }
  }
  #pragma unroll
  for (int c = 0; c < 4; c++)
    o[c] = (acc[c][0]+acc[c][1])+(acc[c][2]+acc[c][3]);
}

// 4 waves per graph (R10 schedule) + D-gather prefetch + hoisted stop-gumbels
// + parallel-exp combines.
__global__ void __launch_bounds__(256, 4)
gfn_fused(const float* __restrict__ node_tokens,
          const float* __restrict__ edge_emb,
          const float* __restrict__ Wf1, const float* __restrict__ Wnf, const float* __restrict__ Wf2,
          const float* __restrict__ bf,  const float* __restrict__ wf,
          const float* __restrict__ Wb1, const float* __restrict__ Wnb, const float* __restrict__ Wb2,
          const float* __restrict__ bb,  const float* __restrict__ wb,
          const float* __restrict__ w_stop, const float* __restrict__ b_stop,
          const float* __restrict__ Ws,  const float* __restrict__ Wu, const float* __restrict__ bu,
          const int* __restrict__ e_src, const int* __restrict__ e_dst,
          float* __restrict__ out, KeysArg keys)
{
  const int g    = blockIdx.x;
  const int tid  = threadIdx.x;
  const int lane = tid & 63;
  const int wave = tid >> 6;
  const int ebase = g * EPG;

  __shared__ uint8_t  srcL[EPG], dstL[EPG];
  __shared__ uint16_t listO[EPG], listI[EPG];
  __shared__ int cntO[NPG], cntI[NPG], begO[NPG], begI[NPG];
  __shared__ uint8_t usedL[EPG];
  __shared__ float st_sh[DD];
  __shared__ float u_sh[DD], nt_sh[DD], acs_sh[DD];
  __shared__ float ntb_sh[DD], ntN_sh[DD], uN_sh[DD], ubB_sh[DD];
  __shared__ float xcF[MAXDEG], gmF[MAXDEG], xcB[MAXDEG];
  __shared__ float sl_sh, xbb_sh;

  // ---- load edges, init ----
  for (int j = tid; j < EPG; j += 256){
    srcL[j] = (uint8_t)(e_src[ebase+j] - g*NPG);
    dstL[j] = (uint8_t)(e_dst[ebase+j] - g*NPG);
    usedL[j] = 0;
  }
  for (int n = tid; n < NPG; n += 256){ cntO[n]=0; cntI[n]=0; }
  if (tid < DD) st_sh[tid] = 0.f;
  __syncthreads();

  for (int j = tid; j < EPG; j += 256){
    atomicAdd(&cntO[srcL[j]], 1);
    atomicAdd(&cntI[dstL[j]], 1);
  }
  __syncthreads();

  if (wave == 0){
    int n0 = lane*2, n1 = n0+1;
    int c0O=cntO[n0], c1O=cntO[n1], sO=c0O+c1O;
    int c0I=cntI[n0], c1I=cntI[n1], sI=c0I+c1I;
    int xO=sO, xI=sI;
    #pragma unroll
    for (int off=1; off<64; off<<=1){
      int tO=__shfl_up(xO,off,64), tI=__shfl_up(xI,off,64);
      if (lane>=off){ xO+=tO; xI+=tI; }
    }
    begO[n0]=xO-sO; begO[n1]=xO-c1O;
    begI[n0]=xI-sI; begI[n1]=xI-c1I;
  }
  __syncthreads();
  for (int n = tid; n < NPG; n += 256){ cntO[n]=0; cntI[n]=0; }
  __syncthreads();

  for (int ph = 0; ph < WAVES; ph++){
    if (wave == ph){
      #pragma unroll
      for (int h = 0; h < 2; h++){
        int j = ph*128 + h*64 + lane;
        int sL = srcL[j]; int p = atomicAdd(&cntO[sL],1); listO[begO[sL]+p] = (uint16_t)j;
        int dL = dstL[j]; int q = atomicAdd(&cntI[dL],1); listI[begI[dL]+q] = (uint16_t)j;
      }
    }
    __syncthreads();
  }

  const float bf_l = bf[lane], wf_l = wf[lane];
  const float bb_l = bb[lane], wb_l = wb[lane];
  const float bu_l = bu[lane], wst_l = w_stop[lane];
  const float bstop = b_stop[0];

  // ---- hoisted per-step stop-gumbels (lane s holds step s's value) ----
  float gsv;
  {
    uint32_t k0 = keys.ks0[0], k1 = keys.ks1[0];
    #pragma unroll
    for (int s5 = 1; s5 < NSTEP; s5++)
      if (lane == s5){ k0 = keys.ks0[s5]; k1 = keys.ks1[s5]; }
    gsv = (lane < NSTEP) ? gumbel_part(k0, k1, (uint32_t)g) : 0.f;
  }

  bool done = false;
  int stepsC = 0, stopn = -1, activeL = 0;
  float lpf_sum = 0.f;
  int bOF = begO[0], dOF = min(cntO[0], MAXDEG);

  // ---- prologue: Phase A (dense) + A2 (fwd candidates for step 0) ----
  {
    float st_v = st_sh[lane];
    if (wave == 0)      u_sh[lane]   = matvec_col(Wf2, st_v, lane);
    else if (wave == 1){ float ntv = node_tokens[(size_t)(g*NPG+0)*DD+lane];
                         nt_sh[lane] = matvec_col(Wnf, ntv, lane); }
    else if (wave == 2) acs_sh[lane] = matvec_col(Ws, st_v, lane);   // speculative
    else {
      float sl = wsum(st_v * wst_l) + bstop;
      if (lane == 0) sl_sh = sl;
      if (lane < dOF)
        gmF[lane] = gumbel_part(keys.ke0[0], keys.ke1[0], (uint32_t)(ebase + listO[bOF+lane]));
    }
    __syncthreads();
    if (wave >= 2){
      for (int c = wave-2; c < (dOF+3)>>2; c += 2){
        int el[4]; float v[4];
        #pragma unroll
        for (int t = 0; t < 4; t++){
          int k = c*4 + t;
          el[t] = listO[bOF + min(k, dOF-1)];
          v[t]  = edge_emb[(size_t)(ebase+el[t])*DD + lane];
        }
        float o[4], x[4];
        matvec4(Wf1, v[0], v[1], v[2], v[3], lane, o);
        #pragma unroll
        for (int t = 0; t < 4; t++) x[t] = fmaxf(o[t] + nt_sh[lane] + bf_l + u_sh[lane], 0.f) * wf_l;
        wsum4(x[0], x[1], x[2], x[3]);
        #pragma unroll
        for (int t = 0; t < 4; t++){
          int k = c*4 + t;
          if (k < dOF && lane == 0) xcF[k] = usedL[el[t]] ? NEGF : x[t];
        }
      }
    }
    __syncthreads();
  }

  for (int s = 0; s < NSTEP; s++){
    float act_out = -1.f, lpf_out = 0.f, lpb_out = 0.f;
    if (!done){
      // ---- selection ----
      float xr = (lane < MAXDEG) ? xcF[lane] : NEGF;
      float gr = (lane < MAXDEG) ? gmF[lane] : 0.f;
      int   er = (lane < dOF)    ? (int)listO[bOF + lane] : -1;
      float sl = sl_sh;

      float m1 = NEGF; int nvalid = 0;
      for (int k=0;k<dOF;k++){ float xk=rdlane(xr,k); if (xk!=NEGF){ m1=fmaxf(m1,xk); nvalid++; } }
      // parallel exp, serial masked sum (order & bits identical to serial expf loop)
      float ex = expf(xr - m1);
      float ssum = 0.f;
      for (int k=0;k<dOF;k++){ float xk=rdlane(xr,k); if (xk!=NEGF) ssum += rdlane(ex,k); }
      const bool has_edge = nvalid > 0;
      float lse_e = m1 + logf(fmaxf(ssum, 1e-30f));
      const bool allow_stop = (stepsC < 4);
      float stop_t = allow_stop ? sl : NEGF;
      float amx = fmaxf(lse_e, stop_t);
      float Z = amx + log1pf(expf(-fabsf(lse_e - stop_t)));

      float mbest = NEGF; int elbest = -1; float xbest = 0.f;
      for (int k=0;k<dOF;k++){
        float xk = rdlane(xr,k);
        if (xk == NEGF) continue;
        float se = (xk - Z) + rdlane(gr,k);
        if (se > mbest){ mbest = se; elbest = rdlane_i(er,k); xbest = xk; }
      }
      float gs = rdlane(gsv, s);
      float ss = allow_stop ? (sl - Z) + gs : NEGF;
      float mcmp = has_edge ? mbest : NEGF;
      const bool choose_stop = (ss > mcmp) || (!has_edge);
      float logp_stop = allow_stop ? (sl - Z) : 0.f;
      const bool take_edge = !choose_stop;

      act_out = choose_stop ? -1.f : (float)(ebase + elbest);
      lpf_out = choose_stop ? logp_stop : (xbest - Z);
      if (choose_stop && stopn < 0) stopn = activeL;

      if (take_edge){
        const int newA = dstL[elbest];
        const bool more = (s < NSTEP-1);
        const int bI  = begI[newA], dIc = min(cntI[newA], MAXDEG);
        const int bON = begO[newA];
        const int dON = more ? min(cntO[newA], MAXDEG) : 0;

        // ---- PREFETCH first D-chunk edge rows (ride out through B+C) ----
        float vPre[4]; int elPre[4]; bool pre = false; int c0;
        if (wave == 2 || wave == 0){
          c0 = (wave==2 ? 0 : 1);
          if (c0 < ((dIc+3)>>2)){
            pre = true;
            #pragma unroll
            for (int t = 0; t < 4; t++){
              int k = c0*4 + t;
              elPre[t] = listI[bI + min(k, dIc-1)];
              vPre[t]  = edge_emb[(size_t)(ebase+elPre[t])*DD + lane];
            }
          }
        } else {
          c0 = (wave==3 ? 0 : 1);
          if (c0 < ((dON+3)>>2)){
            pre = true;
            #pragma unroll
            for (int t = 0; t < 4; t++){
              int k = c0*4 + t;
              elPre[t] = listO[bON + min(k, dON-1)];
              vPre[t]  = edge_emb[(size_t)(ebase+elPre[t])*DD + lane];
            }
          }
        }

        // ---- Phase B: state' + node-token matvecs ----
        if (wave == 0){
          float rv = edge_emb[(size_t)(ebase+elbest)*DD + lane];
          float acr = matvec_col(Wu, rv, lane);
          st_sh[lane] = tanhf(acs_sh[lane] + acr + bu_l);
          if (lane == 0) usedL[elbest] = 1;
        } else if (wave == 1){
          float nbv = node_tokens[(size_t)(g*NPG + newA)*DD + lane];
          ntb_sh[lane] = matvec_col(Wnb, nbv, lane);
        } else if (wave == 2){
          if (more){
            float nbv = node_tokens[(size_t)(g*NPG + newA)*DD + lane];
            ntN_sh[lane] = matvec_col(Wnf, nbv, lane);
          }
        }
        activeL = newA; stepsC++;
        __syncthreads();

        // ---- Phase C: st'-dependent matvecs + next edge-gumbels ----
        float stp = st_sh[lane];
        if (wave == 0){
          if (more) uN_sh[lane] = matvec_col(Wf2, stp, lane);
        } else if (wave == 1){
          ubB_sh[lane] = matvec_col(Wb2, stp, lane);
        } else if (wave == 2){
          if (more) acs_sh[lane] = matvec_col(Ws, stp, lane);
        } else {
          if (more){
            float s2 = wsum(stp * wst_l) + bstop;
            if (lane == 0) sl_sh = s2;
            if (lane < dON)
              gmF[lane] = gumbel_part(keys.ke0[s+1], keys.ke1[s+1],
                                      (uint32_t)(ebase + listO[bON+lane]));
          }
        }
        __syncthreads();

        // ---- Phase D ----
        if (wave == 2 || wave == 0){
          for (int c = c0; c < (dIc+3)>>2; c += 2){
            int el[4]; float v[4];
            if (pre && c == c0){
              #pragma unroll
              for (int t = 0; t < 4; t++){ el[t] = elPre[t]; v[t] = vPre[t]; }
            } else {
              #pragma unroll
              for (int t = 0; t < 4; t++){
                int k = c*4 + t;
                el[t] = listI[bI + min(k, dIc-1)];
                v[t]  = edge_emb[(size_t)(ebase+el[t])*DD + lane];
              }
            }
            float o[4], xb[4];
            matvec4(Wb1, v[0], v[1], v[2], v[3], lane, o);
            #pragma unroll
            for (int t = 0; t < 4; t++) xb[t] = fmaxf(o[t] + ntb_sh[lane] + bb_l + ubB_sh[lane], 0.f) * wb_l;
            wsum4(xb[0], xb[1], xb[2], xb[3]);
            #pragma unroll
            for (int t = 0; t < 4; t++){
              int k = c*4 + t;
              if (k < dIc && lane == 0){
                xcB[k] = xb[t];
                if (el[t] == elbest) xbb_sh = xb[t];
              }
            }
          }
        } else {
          for (int c = c0; c < (dON+3)>>2; c += 2){
            int el[4]; float v[4];
            if (pre && c == c0){
              #pragma unroll
              for (int t = 0; t < 4; t++){ el[t] = elPre[t]; v[t] = vPre[t]; }
            } else {
              #pragma unroll
              for (int t = 0; t < 4; t++){
                int k = c*4 + t;
                el[t] = listO[bON + min(k, dON-1)];
                v[t]  = edge_emb[(size_t)(ebase+el[t])*DD + lane];
              }
            }
            float o[4], x[4];
            matvec4(Wf1, v[0], v[1], v[2], v[3], lane, o);
            #pragma unroll
            for (int t = 0; t < 4; t++) x[t] = fmaxf(o[t] + ntN_sh[lane] + bf_l + uN_sh[lane], 0.f) * wf_l;
            wsum4(x[0], x[1], x[2], x[3]);
            #pragma unroll
            for (int t = 0; t < 4; t++){
              int k = c*4 + t;
              if (k < dON && lane == 0) xcF[k] = usedL[el[t]] ? NEGF : x[t];
            }
          }
        }
        __syncthreads();

        // ---- bwd combine (parallel exp, serial masked sum) ----
        float xbr = (lane < MAXDEG) ? xcB[lane] : 0.f;
        float m2 = NEGF;
        for (int k=0;k<dIc;k++) m2 = fmaxf(m2, rdlane(xbr,k));
        float ex2 = expf(xbr - m2);
        float s2 = 0.f;
        for (int k=0;k<dIc;k++) s2 += rdlane(ex2,k);
        float lse_b = m2 + logf(fmaxf(s2, 1e-30f));
        lpb_out = xbb_sh - lse_b;

        bOF = bON; dOF = dON;
      }
      done = done || choose_stop;
    }

    if (tid == 0){
      out[OA  + g*NSTEP + s] = act_out;
      out[OPF + g*NSTEP + s] = lpf_out;
      out[OPB + g*NSTEP + s] = lpb_out;
    }
    lpf_sum += lpf_out;
  }

  // ---- finalize ----
  if (tid == 0){
    out[OLS + g] = lpf_sum;
    int sn = (stopn < 0) ? activeL : stopn;
    out[OSN + g] = (float)sn;
    out[OST + g] = (float)stepsC;
  }
  for (int j = tid; j < EPG; j += 256)
    out[OU + ebase + j] = usedL[j] ? 1.0f : 0.0f;
}

extern "C" void kernel_launch(void* const* d_in, const int* in_sizes, int n_in,
                              void* d_out, int out_size, void* d_ws, size_t ws_size,
                              hipStream_t stream)
{
  (void)in_sizes; (void)n_in; (void)out_size; (void)d_ws; (void)ws_size;

  // JAX key schedule, threefry_partitionable (default since jax 0.4.36)
  KeysArg K;
  for (uint32_t s = 0; s < NSTEP; s++){
    uint32_t a = 0u, b = s;
    tf2x32(0u, 42u, a, b);
    uint32_t e0 = 0u, e1 = 0u;
    tf2x32(a, b, e0, e1);
    uint32_t s0 = 0u, s1 = 1u;
    tf2x32(a, b, s0, s1);
    K.ke0[s] = e0; K.ke1[s] = e1;
    K.ks0[s] = s0; K.ks1[s] = s1;
  }

  const int* eidx = (const int*)d_in[17];
  gfn_fused<<<dim3(NBLK), dim3(256), 0, stream>>>(
      (const float*)d_in[0],  (const float*)d_in[1],
      (const float*)d_in[2],  (const float*)d_in[3],  (const float*)d_in[4],
      (const float*)d_in[5],  (const float*)d_in[6],
      (const float*)d_in[7],  (const float*)d_in[8],  (const float*)d_in[9],
      (const float*)d_in[10], (const float*)d_in[11],
      (const float*)d_in[12], (const float*)d_in[13],
      (const float*)d_in[14], (const float*)d_in[15], (const float*)d_in[16],
      eidx, eidx + ETOT,
      (float*)d_out, K);
}